// Round 7
// baseline (337.369 us; speedup 1.0000x reference)
//
#include <hip/hip_runtime.h>
#include <stdint.h>

#define NN 50000
#define NE 500000
#define SPB 32
#define NEB (NE / SPB)                        // 15625 edge tiles, exact
#define NT16 3125                             // NN/16 exactly (k_hp / k_out grids)
#define ST16 (NT16 * 256)                     // 800000 grid-stride
#define NBLK_N ((NN + 255) / 256)             // 196

typedef short bf16x8 __attribute__((ext_vector_type(8)));
typedef float f32x4 __attribute__((ext_vector_type(4)));
typedef unsigned short u16;
typedef unsigned short u16x4 __attribute__((ext_vector_type(4)));
typedef unsigned short u16x8 __attribute__((ext_vector_type(8)));
typedef unsigned int u32x2 __attribute__((ext_vector_type(2)));
typedef unsigned int u32x4 __attribute__((ext_vector_type(4)));

__device__ __forceinline__ u16 f2b(float x) {
  uint32_t u = __builtin_bit_cast(uint32_t, x);
  return (u16)((u + 0x7fffu + ((u >> 16) & 1u)) >> 16);
}
__device__ __forceinline__ float b2f(uint32_t lo16) {
  return __builtin_bit_cast(float, lo16 << 16);
}
// HW packed f32->bf16 (RNE, identical to f2b emulation on normal inputs).
__device__ __forceinline__ uint32_t cvtpk(float lo, float hi) {
  uint32_t r;
  asm("v_cvt_pk_bf16_f32 %0, %1, %2" : "=v"(r) : "v"(lo), "v"(hi));
  return r;
}
__device__ __forceinline__ u16x8 pack8(f32x4 a, f32x4 b) {
  union { uint32_t w[4]; u16x8 v; } u;
  u.w[0] = cvtpk(a[0], a[1]);
  u.w[1] = cvtpk(a[2], a[3]);
  u.w[2] = cvtpk(b[0], b[1]);
  u.w[3] = cvtpk(b[2], b[3]);
  return u.v;
}

// JAX threefry2x32, key = jax.random.key(42) -> (0, 42)
__device__ __forceinline__ void threefry(uint32_t x0, uint32_t x1,
                                         uint32_t& o0, uint32_t& o1) {
  const uint32_t k0 = 0u, k1 = 42u, k2 = 0u ^ 42u ^ 0x1BD11BDAu;
  x0 += k0; x1 += k1;
#define TFR(r) { x0 += x1; x1 = (x1 << r) | (x1 >> (32 - r)); x1 ^= x0; }
  TFR(13) TFR(15) TFR(26) TFR(6)
  x0 += k1; x1 += k2 + 1u;
  TFR(17) TFR(29) TFR(16) TFR(24)
  x0 += k2; x1 += k0 + 2u;
  TFR(13) TFR(15) TFR(26) TFR(6)
  x0 += k0; x1 += k1 + 3u;
  TFR(17) TFR(29) TFR(16) TFR(24)
  x0 += k1; x1 += k2 + 4u;
  TFR(13) TFR(15) TFR(26) TFR(6)
  x0 += k2; x1 += k0 + 5u;
#undef TFR
  o0 = x0; o1 = x1;
}

__device__ __forceinline__ bool jax_keep(uint32_t j) {
  uint32_t o0, o1;
  threefry(0u, j, o0, o1);
  uint32_t bits = o0 ^ o1;
  float u = __builtin_bit_cast(float, (bits >> 9) | 0x3f800000u) - 1.0f;
  return u < 0.9f;
}

// ---- weight images + deg zeroing (fused memset saves a dispatch)
__global__ __launch_bounds__(256) void k_prep(const float* __restrict__ Wmsg,
                                              const float* __restrict__ Wlin,
                                              u16* __restrict__ WhImg,
                                              u16* __restrict__ WcImg,
                                              u16* __restrict__ WlImg,
                                              uint32_t* __restrict__ deg) {
  const int t = threadIdx.x, b = blockIdx.x;
  if (b == 0) {
#pragma unroll
    for (int it = 0; it < 16; ++it) {
      int g = t + (it << 8);
      int d = g >> 5, k4 = (g & 31) << 2;
      u16x4 v = {f2b(Wmsg[(k4 + 0) * 128 + d]), f2b(Wmsg[(k4 + 1) * 128 + d]),
                 f2b(Wmsg[(k4 + 2) * 128 + d]), f2b(Wmsg[(k4 + 3) * 128 + d])};
      *(u16x4*)&WhImg[(d << 7) + k4] = v;
    }
  } else if (b == 1) {
#pragma unroll
    for (int it = 0; it < 8; ++it) {
      int g = t + (it << 8);
      int d = g >> 4, k4 = (g & 15) << 2;
      u16x4 v = {f2b(Wmsg[(128 + k4 + 0) * 128 + d]), f2b(Wmsg[(128 + k4 + 1) * 128 + d]),
                 f2b(Wmsg[(128 + k4 + 2) * 128 + d]), f2b(Wmsg[(128 + k4 + 3) * 128 + d])};
      *(u16x4*)&WcImg[(d << 6) + k4] = v;
    }
  } else if (b == 2) {
#pragma unroll
    for (int it = 0; it < 16; ++it) {
      int g = t + (it << 8);
      int d = g >> 5, k4 = (g & 31) << 2;
      u16x4 v = {f2b(Wlin[(k4 + 0) * 128 + d]), f2b(Wlin[(k4 + 1) * 128 + d]),
                 f2b(Wlin[(k4 + 2) * 128 + d]), f2b(Wlin[(k4 + 3) * 128 + d])};
      *(u16x4*)&WlImg[(d << 7) + k4] = v;
    }
  } else {
    for (int i = ((b - 3) << 8) + t; i < NN; i += 13 * 256) deg[i] = 0u;
  }
}

// ---- scan stage 1: per-256-block exclusive scan + block sums
__global__ __launch_bounds__(256) void k_scan1(const uint32_t* __restrict__ deg,
                                               uint32_t* __restrict__ ex,
                                               uint32_t* __restrict__ bsum) {
  __shared__ uint32_t s[256];
  int t = threadIdx.x;
  int i = blockIdx.x * 256 + t;
  uint32_t v = (i < NN) ? deg[i] : 0u;
  s[t] = v;
  __syncthreads();
#pragma unroll
  for (int off = 1; off < 256; off <<= 1) {
    uint32_t y = (t >= off) ? s[t - off] : 0u;
    __syncthreads();
    s[t] += y;
    __syncthreads();
  }
  if (i < NN) ex[i] = s[t] - v;
  if (t == 255) bsum[blockIdx.x] = s[255];
}

// ---- scan stages 2+3 merged
__global__ __launch_bounds__(256) void k_scan23(const uint32_t* __restrict__ bsum,
                                                const uint32_t* __restrict__ ex,
                                                uint32_t* __restrict__ cursor) {
  __shared__ uint32_t s[256];
  int t = threadIdx.x;
  uint32_t v = (t < NBLK_N) ? bsum[t] : 0u;
  s[t] = v;
  __syncthreads();
#pragma unroll
  for (int off = 1; off < 256; off <<= 1) {
    uint32_t y = (t >= off) ? s[t - off] : 0u;
    __syncthreads();
    s[t] += y;
    __syncthreads();
  }
  const uint32_t boff = s[blockIdx.x] - bsum[blockIdx.x];  // exclusive prefix
  int i = blockIdx.x * 256 + t;
  if (i < NN) cursor[i] = ex[i] + boff;
}

// k_perm: index-only scatter, 4B per edge (halves scattered-line count vs 8B).
__global__ __launch_bounds__(256) void k_perm(const int* __restrict__ ei,
                                              uint32_t* __restrict__ cursor,
                                              int* __restrict__ perm) {
  int i = blockIdx.x * 256 + threadIdx.x;
  if (i < NE) {
    uint32_t d = (uint32_t)ei[NE + i];
    uint32_t pos = atomicAdd(&cursor[d], 1u);
    perm[pos] = i;
  }
}

// K2: SPB=32 edges/block, LDS 16 KB union -> 8 blocks/CU (wave-capped).
// src/dst re-derived from ei (L2/L3-hot broadcast gathers).
__global__ __launch_bounds__(256, 8) void k_edge3(const int* __restrict__ perm,
                                                  const int* __restrict__ ei,
                                                  const float* __restrict__ attr,
                                                  const float* __restrict__ tim,
                                                  const u16* __restrict__ WcImg,
                                                  const u16* __restrict__ Hp,
                                                  float* __restrict__ acc) {
  __shared__ union { u16 A[32 * 64]; float C[32 * 128]; } lds;  // 16 KB
  __shared__ int sdst[32];
  const int t = threadIdx.x;
  const long e0 = (long)blockIdx.x << 5;

  const int row = t >> 3, g = t & 7;
  const int e = perm[e0 + row];      // broadcast within 8-thread group
  const int src = ei[e];             // random 4B, L2/L3-hot, broadcast
  const float* src8 = (g < 4) ? (attr + ((size_t)e << 5) + (g << 3))
                              : (tim + ((size_t)e << 5) + ((g - 4) << 3));
  f32x4 v0 = *(const f32x4*)src8;
  f32x4 v1 = *(const f32x4*)(src8 + 4);
  *(u16x8*)&lds.A[(row << 6) + ((g ^ (row & 7)) << 3)] = pack8(v0, v1);
  const u32x4 hpA = *(const u32x4*)(Hp + ((size_t)src << 7) + (g << 4));
  const u32x4 hpB = *(const u32x4*)(Hp + ((size_t)src << 7) + (g << 4) + 8);
  if (g == 0) sdst[row] = ei[NE + e];
  __syncthreads();

  const int lane = t & 63, w = t >> 6;
  const int quad = lane >> 4, lr = lane & 15;
  f32x4 c[2][2];
#pragma unroll
  for (int i = 0; i < 2; ++i)
#pragma unroll
    for (int j = 0; j < 2; ++j) { f32x4 z = {0.f, 0.f, 0.f, 0.f}; c[i][j] = z; }
#pragma unroll
  for (int ks = 0; ks < 64; ks += 32) {
    const int gi = (ks >> 3) + quad;
    bf16x8 a[2], b[2];
#pragma unroll
    for (int i = 0; i < 2; ++i) {
      int r2 = (i << 4) + lr;
      a[i] = *(const bf16x8*)&lds.A[(r2 << 6) + ((gi ^ (r2 & 7)) << 3)];
    }
#pragma unroll
    for (int j = 0; j < 2; ++j) {
      int col = (w << 5) + (j << 4) + lr;
      b[j] = *(const bf16x8*)&WcImg[(col << 6) + (gi << 3)];
    }
#pragma unroll
    for (int i = 0; i < 2; ++i)
#pragma unroll
      for (int j = 0; j < 2; ++j)
        c[i][j] = __builtin_amdgcn_mfma_f32_16x16x32_bf16(a[i], b[j], c[i][j], 0, 0, 0);
  }
  __syncthreads();  // A consumed; C may overwrite
#pragma unroll
  for (int i = 0; i < 2; ++i)
#pragma unroll
    for (int j = 0; j < 2; ++j)
#pragma unroll
      for (int r = 0; r < 4; ++r) {
        int rr = (i << 4) + (quad << 2) + r;
        int col = (w << 5) + (j << 4) + lr;
        lds.C[(rr << 7) + ((((col >> 2) ^ rr) << 2) + (col & 3))] = c[i][j][r];
      }
  __syncthreads();
  // stage 1: msg = relu(P + Hp[src]); thread (row,g) owns cols g*16..+15
  {
#pragma unroll
    for (int gg = 0; gg < 4; ++gg) {
      int cb4 = (g << 2) + gg;  // col/4
      float* p = &lds.C[(row << 7) + ((cb4 ^ row) << 2)];
      f32x4 cv = *(const f32x4*)p;
      const u32x4 hw = (gg < 2) ? hpA : hpB;
      const int k = (gg & 1) << 1;
      uint32_t w0 = hw[k], w1 = hw[k + 1];
      cv[0] = fmaxf(cv[0] + b2f(w0 & 0xffffu), 0.f);
      cv[1] = fmaxf(cv[1] + b2f(w0 >> 16), 0.f);
      cv[2] = fmaxf(cv[2] + b2f(w1 & 0xffffu), 0.f);
      cv[3] = fmaxf(cv[3] + b2f(w1 >> 16), 0.f);
      *(f32x4*)p = cv;
    }
  }
  __syncthreads();
  // stage 2: segmented reduction, 2 halves x 16 slots, 128 cols
  {
    const int col = t & 127, half = t >> 7;
    const int beg = half << 4, end = beg + 16;
    int cur = sdst[beg];
    float sum = 0.f;
    int runstart = beg;
    for (int ss = beg; ss < end; ++ss) {
      int d = sdst[ss];
      if (d != cur) {
        if (cur >= 0) {
          float* p = acc + ((size_t)cur << 7) + col;
          if (runstart == beg) unsafeAtomicAdd(p, sum);
          else *p = sum;
        }
        cur = d; sum = 0.f; runstart = ss;
      }
      sum += lds.C[(ss << 7) + ((((col >> 2) ^ ss) << 2) + (col & 3))];
    }
    if (cur >= 0) unsafeAtomicAdd(acc + ((size_t)cur << 7) + col, sum);
  }
}

// K1: Hp = bf16(hidden @ W_msg[0:128,:] + b_msg). 16-row tiles, coalesced
// u16x8 Hp stores via LDS repack. Fused deg + acc zero.
__global__ __launch_bounds__(256) void k_hp(const float* __restrict__ hidden,
                                            const u16* __restrict__ WhImg,
                                            const float* __restrict__ bmsg,
                                            const int* __restrict__ ei,
                                            uint32_t* __restrict__ deg,
                                            u16* __restrict__ Hp,
                                            float* __restrict__ acc) {
  __shared__ union { u16 A[16 * 128]; float C[16 * 128]; } lds;  // 8 KB
  const int t = threadIdx.x;
  const int row0 = blockIdx.x << 4;
  {
    f32x4* acc4 = (f32x4*)acc;
    const f32x4 z = {0.f, 0.f, 0.f, 0.f};
    for (int i = blockIdx.x * 256 + t; i < NN * 32; i += ST16) acc4[i] = z;
  }
  {
    int i = blockIdx.x * 256 + t;
    if (i < NE) atomicAdd(&deg[ei[NE + i]], 1u);
  }
  const int srow = t >> 4, sq = t & 15;  // 16 threads/row, 8 cols each
  {
    const float* hp8 = hidden + ((size_t)(row0 + srow) << 7) + (sq << 3);
    f32x4 v0 = *(const f32x4*)hp8;
    f32x4 v1 = *(const f32x4*)(hp8 + 4);
    *(u16x8*)&lds.A[(srow << 7) + ((sq ^ srow) << 3)] = pack8(v0, v1);
  }
  __syncthreads();
  const int lane = t & 63, w = t >> 6;
  const int quad = lane >> 4, lr = lane & 15;
  f32x4 c[2];
#pragma unroll
  for (int j = 0; j < 2; ++j) { f32x4 z = {0.f, 0.f, 0.f, 0.f}; c[j] = z; }
#pragma unroll
  for (int ks = 0; ks < 128; ks += 32) {
    const int gi = (ks >> 3) + quad;
    bf16x8 a = *(const bf16x8*)&lds.A[(lr << 7) + ((gi ^ lr) << 3)];
#pragma unroll
    for (int j = 0; j < 2; ++j) {
      int col = (w << 5) + (j << 4) + lr;
      bf16x8 b = *(const bf16x8*)&WhImg[(col << 7) + (gi << 3)];
      c[j] = __builtin_amdgcn_mfma_f32_16x16x32_bf16(a, b, c[j], 0, 0, 0);
    }
  }
  __syncthreads();  // A consumed
#pragma unroll
  for (int j = 0; j < 2; ++j) {
    int col = (w << 5) + (j << 4) + lr;
    float bias = bmsg[col];
    int g4 = col >> 2;
#pragma unroll
    for (int r = 0; r < 4; ++r) {
      int rr = (quad << 2) + r;
      lds.C[(rr << 7) + (((g4 ^ (rr & 7)) << 2) + (col & 3))] = c[j][r] + bias;
    }
  }
  __syncthreads();
  {
    const f32x4* C4 = (const f32x4*)lds.C;
    f32x4 v0 = C4[(srow << 5) + (((sq << 1) | 0) ^ (srow & 7))];
    f32x4 v1 = C4[(srow << 5) + (((sq << 1) | 1) ^ (srow & 7))];
    *(u16x8*)&Hp[((size_t)(row0 + srow) << 7) + (sq << 3)] = pack8(v0, v1);
  }
}

// K3 (in-place): out = dropout(relu(LN((acc+boundary) @ W_lin + b_lin)))
__global__ __launch_bounds__(256) void k_out(float* accout,
                                             const float* __restrict__ bnd,
                                             const u16* __restrict__ WlImg,
                                             const float* __restrict__ blin,
                                             const float* __restrict__ gam,
                                             const float* __restrict__ bet) {
  __shared__ union { u16 A[16 * 128]; float C[16 * 128]; } lds;  // 8 KB
  const int t = threadIdx.x;
  const int row0 = blockIdx.x << 4;
  const int srow = t >> 4, sq = t & 15;
  const int n = row0 + srow;
  {
    const float* ap = accout + ((size_t)n << 7) + (sq << 3);
    const float* bp = bnd + ((size_t)n << 7) + (sq << 3);
    f32x4 a0 = *(const f32x4*)ap, a1 = *(const f32x4*)(ap + 4);
    f32x4 b0 = *(const f32x4*)bp, b1 = *(const f32x4*)(bp + 4);
    *(u16x8*)&lds.A[(srow << 7) + ((sq ^ srow) << 3)] = pack8(a0 + b0, a1 + b1);
  }
  __syncthreads();
  const int lane = t & 63, w = t >> 6;
  const int quad = lane >> 4, lr = lane & 15;
  f32x4 c[2];
#pragma unroll
  for (int j = 0; j < 2; ++j) { f32x4 z = {0.f, 0.f, 0.f, 0.f}; c[j] = z; }
#pragma unroll
  for (int ks = 0; ks < 128; ks += 32) {
    const int gi = (ks >> 3) + quad;
    bf16x8 a = *(const bf16x8*)&lds.A[(lr << 7) + ((gi ^ lr) << 3)];
#pragma unroll
    for (int j = 0; j < 2; ++j) {
      int col = (w << 5) + (j << 4) + lr;
      bf16x8 b = *(const bf16x8*)&WlImg[(col << 7) + (gi << 3)];
      c[j] = __builtin_amdgcn_mfma_f32_16x16x32_bf16(a, b, c[j], 0, 0, 0);
    }
  }
  __syncthreads();  // A consumed
#pragma unroll
  for (int j = 0; j < 2; ++j) {
    int col = (w << 5) + (j << 4) + lr;
    float bias = blin[col];
    int g4 = col >> 2;
#pragma unroll
    for (int r = 0; r < 4; ++r) {
      int rr = (quad << 2) + r;
      lds.C[(rr << 7) + (((g4 ^ (rr & 7)) << 2) + (col & 3))] = c[j][r] + bias;
    }
  }
  __syncthreads();
  // LN + relu + dropout: 16 threads/row, thread sq owns cols sq*8..+7
  const f32x4* C4 = (const f32x4*)lds.C;
  f32x4 x0 = C4[(srow << 5) + (((sq << 1) | 0) ^ (srow & 7))];
  f32x4 x1 = C4[(srow << 5) + (((sq << 1) | 1) ^ (srow & 7))];
  float s1 = 0.f, s2 = 0.f;
#pragma unroll
  for (int m = 0; m < 4; ++m) {
    s1 += x0[m] + x1[m];
    s2 += x0[m] * x0[m] + x1[m] * x1[m];
  }
  s1 += __shfl_xor(s1, 1, 64); s1 += __shfl_xor(s1, 2, 64);
  s1 += __shfl_xor(s1, 4, 64); s1 += __shfl_xor(s1, 8, 64);
  s2 += __shfl_xor(s2, 1, 64); s2 += __shfl_xor(s2, 2, 64);
  s2 += __shfl_xor(s2, 4, 64); s2 += __shfl_xor(s2, 8, 64);
  const float mean = s1 * 0.0078125f;
  const float var = s2 * 0.0078125f - mean * mean;
  const float inv = 1.0f / sqrtf(var + 1e-5f);
  const int d0 = sq << 3;
  f32x4 gm0 = *(const f32x4*)(gam + d0), gm1 = *(const f32x4*)(gam + d0 + 4);
  f32x4 bb0 = *(const f32x4*)(bet + d0), bb1 = *(const f32x4*)(bet + d0 + 4);
  f32x4 o0, o1;
#pragma unroll
  for (int m = 0; m < 4; ++m) {
    float y0 = fmaxf((x0[m] - mean) * inv * gm0[m] + bb0[m], 0.f);
    float y1 = fmaxf((x1[m] - mean) * inv * gm1[m] + bb1[m], 0.f);
    uint32_t j0 = ((uint32_t)n << 7) + (uint32_t)(d0 + m);
    uint32_t j1 = j0 + 4u;
    o0[m] = jax_keep(j0) ? (y0 * (1.0f / 0.9f)) : 0.0f;
    o1[m] = jax_keep(j1) ? (y1 * (1.0f / 0.9f)) : 0.0f;
  }
  *(f32x4*)(accout + ((size_t)n << 7) + d0) = o0;
  *(f32x4*)(accout + ((size_t)n << 7) + d0 + 4) = o1;
}

extern "C" void kernel_launch(void* const* d_in, const int* in_sizes, int n_in,
                              void* d_out, int out_size, void* d_ws, size_t ws_size,
                              hipStream_t stream) {
  (void)in_sizes; (void)n_in; (void)out_size; (void)ws_size;
  const float* hidden = (const float*)d_in[0];
  const int*   ei     = (const int*)d_in[1];
  const float* attr   = (const float*)d_in[2];
  const float* tim    = (const float*)d_in[3];
  const float* bnd    = (const float*)d_in[4];
  const float* Wmsg   = (const float*)d_in[5];
  const float* bmsg   = (const float*)d_in[6];
  const float* Wlin   = (const float*)d_in[7];
  const float* blin   = (const float*)d_in[8];
  const float* gam    = (const float*)d_in[9];
  const float* bet    = (const float*)d_in[10];

  float* acc = (float*)d_out;  // [N,128] f32 accumulator, finalized in-place

  char* ws = (char*)d_ws;
  u16*      Hp     = (u16*)(ws + 0);              // 12,800,000
  u16*      WhImg  = (u16*)(ws + 12800000);       //     32,768
  u16*      WcImg  = (u16*)(ws + 12832768);       //     16,384
  u16*      WlImg  = (u16*)(ws + 12849152);       //     32,768
  uint32_t* deg    = (uint32_t*)(ws + 12881920);  //    200,000
  uint32_t* cursor = (uint32_t*)(ws + 13081920);  //    200,000
  uint32_t* bsum   = (uint32_t*)(ws + 13281920);  //      1,024
  uint32_t* ex     = (uint32_t*)(ws + 13282944);  //    200,000
  int*      perm   = (int*)(ws + 13482944);       //  2,000,000 (NE*4)
  // total 15,482,944 bytes

  k_prep  <<<dim3(16), dim3(256), 0, stream>>>(Wmsg, Wlin, WhImg, WcImg, WlImg, deg);
  k_hp    <<<dim3(NT16), dim3(256), 0, stream>>>(hidden, WhImg, bmsg, ei, deg, Hp, acc);
  k_scan1 <<<dim3(NBLK_N), dim3(256), 0, stream>>>(deg, ex, bsum);
  k_scan23<<<dim3(NBLK_N), dim3(256), 0, stream>>>(bsum, ex, cursor);
  k_perm  <<<dim3((NE + 255) / 256), dim3(256), 0, stream>>>(ei, cursor, perm);
  k_edge3 <<<dim3(NEB), dim3(256), 0, stream>>>(perm, ei, attr, tim, WcImg, Hp, acc);
  k_out   <<<dim3(NT16), dim3(256), 0, stream>>>(acc, bnd, WlImg, blin, gam, bet);
}

// Round 8
// 330.855 us; speedup vs baseline: 1.0197x; 1.0197x over previous
//
#include <hip/hip_runtime.h>
#include <stdint.h>

#define NN 50000
#define NE 500000
#define SPB 32
#define NEB (NE / SPB)                        // 15625 edge tiles, exact
#define NT16 3125                             // NN/16 exactly (k_hp / k_out grids)
#define ST16 (NT16 * 256)                     // 800000 grid-stride
#define NBLK_N ((NN + 255) / 256)             // 196

typedef short bf16x8 __attribute__((ext_vector_type(8)));
typedef float f32x4 __attribute__((ext_vector_type(4)));
typedef unsigned short u16;
typedef unsigned short u16x4 __attribute__((ext_vector_type(4)));
typedef unsigned short u16x8 __attribute__((ext_vector_type(8)));
typedef unsigned int u32x2 __attribute__((ext_vector_type(2)));
typedef unsigned int u32x4 __attribute__((ext_vector_type(4)));

__device__ __forceinline__ u16 f2b(float x) {
  uint32_t u = __builtin_bit_cast(uint32_t, x);
  return (u16)((u + 0x7fffu + ((u >> 16) & 1u)) >> 16);
}
__device__ __forceinline__ float b2f(uint32_t lo16) {
  return __builtin_bit_cast(float, lo16 << 16);
}
// HW packed f32->bf16 (RNE, identical to f2b emulation on normal inputs).
__device__ __forceinline__ uint32_t cvtpk(float lo, float hi) {
  uint32_t r;
  asm("v_cvt_pk_bf16_f32 %0, %1, %2" : "=v"(r) : "v"(lo), "v"(hi));
  return r;
}
__device__ __forceinline__ u16x8 pack8(f32x4 a, f32x4 b) {
  union { uint32_t w[4]; u16x8 v; } u;
  u.w[0] = cvtpk(a[0], a[1]);
  u.w[1] = cvtpk(a[2], a[3]);
  u.w[2] = cvtpk(b[0], b[1]);
  u.w[3] = cvtpk(b[2], b[3]);
  return u.v;
}

// JAX threefry2x32, key = jax.random.key(42) -> (0, 42)
__device__ __forceinline__ void threefry(uint32_t x0, uint32_t x1,
                                         uint32_t& o0, uint32_t& o1) {
  const uint32_t k0 = 0u, k1 = 42u, k2 = 0u ^ 42u ^ 0x1BD11BDAu;
  x0 += k0; x1 += k1;
#define TFR(r) { x0 += x1; x1 = (x1 << r) | (x1 >> (32 - r)); x1 ^= x0; }
  TFR(13) TFR(15) TFR(26) TFR(6)
  x0 += k1; x1 += k2 + 1u;
  TFR(17) TFR(29) TFR(16) TFR(24)
  x0 += k2; x1 += k0 + 2u;
  TFR(13) TFR(15) TFR(26) TFR(6)
  x0 += k0; x1 += k1 + 3u;
  TFR(17) TFR(29) TFR(16) TFR(24)
  x0 += k1; x1 += k2 + 4u;
  TFR(13) TFR(15) TFR(26) TFR(6)
  x0 += k2; x1 += k0 + 5u;
#undef TFR
  o0 = x0; o1 = x1;
}

__device__ __forceinline__ bool jax_keep(uint32_t j) {
  uint32_t o0, o1;
  threefry(0u, j, o0, o1);
  uint32_t bits = o0 ^ o1;
  float u = __builtin_bit_cast(float, (bits >> 9) | 0x3f800000u) - 1.0f;
  return u < 0.9f;
}

// ---- weight images + deg zeroing (fused memset saves a dispatch)
__global__ __launch_bounds__(256) void k_prep(const float* __restrict__ Wmsg,
                                              const float* __restrict__ Wlin,
                                              u16* __restrict__ WhImg,
                                              u16* __restrict__ WcImg,
                                              u16* __restrict__ WlImg,
                                              uint32_t* __restrict__ deg) {
  const int t = threadIdx.x, b = blockIdx.x;
  if (b == 0) {
#pragma unroll
    for (int it = 0; it < 16; ++it) {
      int g = t + (it << 8);
      int d = g >> 5, k4 = (g & 31) << 2;
      u16x4 v = {f2b(Wmsg[(k4 + 0) * 128 + d]), f2b(Wmsg[(k4 + 1) * 128 + d]),
                 f2b(Wmsg[(k4 + 2) * 128 + d]), f2b(Wmsg[(k4 + 3) * 128 + d])};
      *(u16x4*)&WhImg[(d << 7) + k4] = v;
    }
  } else if (b == 1) {
#pragma unroll
    for (int it = 0; it < 8; ++it) {
      int g = t + (it << 8);
      int d = g >> 4, k4 = (g & 15) << 2;
      u16x4 v = {f2b(Wmsg[(128 + k4 + 0) * 128 + d]), f2b(Wmsg[(128 + k4 + 1) * 128 + d]),
                 f2b(Wmsg[(128 + k4 + 2) * 128 + d]), f2b(Wmsg[(128 + k4 + 3) * 128 + d])};
      *(u16x4*)&WcImg[(d << 6) + k4] = v;
    }
  } else if (b == 2) {
#pragma unroll
    for (int it = 0; it < 16; ++it) {
      int g = t + (it << 8);
      int d = g >> 5, k4 = (g & 31) << 2;
      u16x4 v = {f2b(Wlin[(k4 + 0) * 128 + d]), f2b(Wlin[(k4 + 1) * 128 + d]),
                 f2b(Wlin[(k4 + 2) * 128 + d]), f2b(Wlin[(k4 + 3) * 128 + d])};
      *(u16x4*)&WlImg[(d << 7) + k4] = v;
    }
  } else {
    for (int i = ((b - 3) << 8) + t; i < NN; i += 13 * 256) deg[i] = 0u;
  }
}

// ---- scan stage 1: per-256-block exclusive scan + block sums
__global__ __launch_bounds__(256) void k_scan1(const uint32_t* __restrict__ deg,
                                               uint32_t* __restrict__ ex,
                                               uint32_t* __restrict__ bsum) {
  __shared__ uint32_t s[256];
  int t = threadIdx.x;
  int i = blockIdx.x * 256 + t;
  uint32_t v = (i < NN) ? deg[i] : 0u;
  s[t] = v;
  __syncthreads();
#pragma unroll
  for (int off = 1; off < 256; off <<= 1) {
    uint32_t y = (t >= off) ? s[t - off] : 0u;
    __syncthreads();
    s[t] += y;
    __syncthreads();
  }
  if (i < NN) ex[i] = s[t] - v;
  if (t == 255) bsum[blockIdx.x] = s[255];
}

// ---- scan stages 2+3 merged
__global__ __launch_bounds__(256) void k_scan23(const uint32_t* __restrict__ bsum,
                                                const uint32_t* __restrict__ ex,
                                                uint32_t* __restrict__ cursor) {
  __shared__ uint32_t s[256];
  int t = threadIdx.x;
  uint32_t v = (t < NBLK_N) ? bsum[t] : 0u;
  s[t] = v;
  __syncthreads();
#pragma unroll
  for (int off = 1; off < 256; off <<= 1) {
    uint32_t y = (t >= off) ? s[t - off] : 0u;
    __syncthreads();
    s[t] += y;
    __syncthreads();
  }
  const uint32_t boff = s[blockIdx.x] - bsum[blockIdx.x];  // exclusive prefix
  int i = blockIdx.x * 256 + t;
  if (i < NN) cursor[i] = ex[i] + boff;
}

// k_perm: index-only scatter, single packed 8B write per edge.
// psd[pos] = {e, src|(dst<<16)}  (R6 structure: avoids ei re-gather in edge3)
__global__ __launch_bounds__(256) void k_perm(const int* __restrict__ ei,
                                              uint32_t* __restrict__ cursor,
                                              u32x2* __restrict__ psd) {
  int i = blockIdx.x * 256 + threadIdx.x;
  if (i < NE) {
    uint32_t s = (uint32_t)ei[i], d = (uint32_t)ei[NE + i];
    uint32_t pos = atomicAdd(&cursor[d], 1u);
    u32x2 pv = {(uint32_t)i, s | (d << 16)};
    psd[pos] = pv;
  }
}

// K2: SPB=32 edges/block, LDS 16 KB union -> 8 blocks/CU (wave-capped).
__global__ __launch_bounds__(256, 8) void k_edge3(const u32x2* __restrict__ psd,
                                                  const float* __restrict__ attr,
                                                  const float* __restrict__ tim,
                                                  const u16* __restrict__ WcImg,
                                                  const u16* __restrict__ Hp,
                                                  float* __restrict__ acc) {
  __shared__ union { u16 A[32 * 64]; float C[32 * 128]; } lds;  // 16 KB
  __shared__ int sdst[32];
  const int t = threadIdx.x;
  const long e0 = (long)blockIdx.x << 5;

  const int row = t >> 3, g = t & 7;
  const u32x2 pv = psd[e0 + row];
  const int e = (int)pv.x;
  const int src = (int)(pv.y & 0xffffu);
  const float* src8 = (g < 4) ? (attr + ((size_t)e << 5) + (g << 3))
                              : (tim + ((size_t)e << 5) + ((g - 4) << 3));
  f32x4 v0 = *(const f32x4*)src8;
  f32x4 v1 = *(const f32x4*)(src8 + 4);
  *(u16x8*)&lds.A[(row << 6) + ((g ^ (row & 7)) << 3)] = pack8(v0, v1);
  const u32x4 hpA = *(const u32x4*)(Hp + ((size_t)src << 7) + (g << 4));
  const u32x4 hpB = *(const u32x4*)(Hp + ((size_t)src << 7) + (g << 4) + 8);
  if (g == 0) sdst[row] = (int)(pv.y >> 16);
  __syncthreads();

  const int lane = t & 63, w = t >> 6;
  const int quad = lane >> 4, lr = lane & 15;
  f32x4 c[2][2];
#pragma unroll
  for (int i = 0; i < 2; ++i)
#pragma unroll
    for (int j = 0; j < 2; ++j) { f32x4 z = {0.f, 0.f, 0.f, 0.f}; c[i][j] = z; }
#pragma unroll
  for (int ks = 0; ks < 64; ks += 32) {
    const int gi = (ks >> 3) + quad;
    bf16x8 a[2], b[2];
#pragma unroll
    for (int i = 0; i < 2; ++i) {
      int r2 = (i << 4) + lr;
      a[i] = *(const bf16x8*)&lds.A[(r2 << 6) + ((gi ^ (r2 & 7)) << 3)];
    }
#pragma unroll
    for (int j = 0; j < 2; ++j) {
      int col = (w << 5) + (j << 4) + lr;
      b[j] = *(const bf16x8*)&WcImg[(col << 6) + (gi << 3)];
    }
#pragma unroll
    for (int i = 0; i < 2; ++i)
#pragma unroll
      for (int j = 0; j < 2; ++j)
        c[i][j] = __builtin_amdgcn_mfma_f32_16x16x32_bf16(a[i], b[j], c[i][j], 0, 0, 0);
  }
  __syncthreads();  // A consumed; C may overwrite
#pragma unroll
  for (int i = 0; i < 2; ++i)
#pragma unroll
    for (int j = 0; j < 2; ++j)
#pragma unroll
      for (int r = 0; r < 4; ++r) {
        int rr = (i << 4) + (quad << 2) + r;
        int col = (w << 5) + (j << 4) + lr;
        lds.C[(rr << 7) + ((((col >> 2) ^ rr) << 2) + (col & 3))] = c[i][j][r];
      }
  __syncthreads();
  // stage 1: msg = relu(P + Hp[src]); thread (row,g) owns cols g*16..+15
  {
#pragma unroll
    for (int gg = 0; gg < 4; ++gg) {
      int cb4 = (g << 2) + gg;  // col/4
      float* p = &lds.C[(row << 7) + ((cb4 ^ row) << 2)];
      f32x4 cv = *(const f32x4*)p;
      const u32x4 hw = (gg < 2) ? hpA : hpB;
      const int k = (gg & 1) << 1;
      uint32_t w0 = hw[k], w1 = hw[k + 1];
      cv[0] = fmaxf(cv[0] + b2f(w0 & 0xffffu), 0.f);
      cv[1] = fmaxf(cv[1] + b2f(w0 >> 16), 0.f);
      cv[2] = fmaxf(cv[2] + b2f(w1 & 0xffffu), 0.f);
      cv[3] = fmaxf(cv[3] + b2f(w1 >> 16), 0.f);
      *(f32x4*)p = cv;
    }
  }
  __syncthreads();
  // stage 2: segmented reduction, 2 halves x 16 slots, 128 cols
  {
    const int col = t & 127, half = t >> 7;
    const int beg = half << 4, end = beg + 16;
    int cur = sdst[beg];
    float sum = 0.f;
    int runstart = beg;
    for (int ss = beg; ss < end; ++ss) {
      int d = sdst[ss];
      if (d != cur) {
        if (cur >= 0) {
          float* p = acc + ((size_t)cur << 7) + col;
          if (runstart == beg) unsafeAtomicAdd(p, sum);
          else *p = sum;
        }
        cur = d; sum = 0.f; runstart = ss;
      }
      sum += lds.C[(ss << 7) + ((((col >> 2) ^ ss) << 2) + (col & 3))];
    }
    if (cur >= 0) unsafeAtomicAdd(acc + ((size_t)cur << 7) + col, sum);
  }
}

// K1: Hp = bf16(hidden @ W_msg[0:128,:] + b_msg). 16-row tiles, coalesced
// u16x8 Hp stores via LDS repack. Fused deg + acc zero.
__global__ __launch_bounds__(256) void k_hp(const float* __restrict__ hidden,
                                            const u16* __restrict__ WhImg,
                                            const float* __restrict__ bmsg,
                                            const int* __restrict__ ei,
                                            uint32_t* __restrict__ deg,
                                            u16* __restrict__ Hp,
                                            float* __restrict__ acc) {
  __shared__ union { u16 A[16 * 128]; float C[16 * 128]; } lds;  // 8 KB
  const int t = threadIdx.x;
  const int row0 = blockIdx.x << 4;
  {
    f32x4* acc4 = (f32x4*)acc;
    const f32x4 z = {0.f, 0.f, 0.f, 0.f};
    for (int i = blockIdx.x * 256 + t; i < NN * 32; i += ST16) acc4[i] = z;
  }
  {
    int i = blockIdx.x * 256 + t;
    if (i < NE) atomicAdd(&deg[ei[NE + i]], 1u);
  }
  const int srow = t >> 4, sq = t & 15;  // 16 threads/row, 8 cols each
  {
    const float* hp8 = hidden + ((size_t)(row0 + srow) << 7) + (sq << 3);
    f32x4 v0 = *(const f32x4*)hp8;
    f32x4 v1 = *(const f32x4*)(hp8 + 4);
    *(u16x8*)&lds.A[(srow << 7) + ((sq ^ srow) << 3)] = pack8(v0, v1);
  }
  __syncthreads();
  const int lane = t & 63, w = t >> 6;
  const int quad = lane >> 4, lr = lane & 15;
  f32x4 c[2];
#pragma unroll
  for (int j = 0; j < 2; ++j) { f32x4 z = {0.f, 0.f, 0.f, 0.f}; c[j] = z; }
#pragma unroll
  for (int ks = 0; ks < 128; ks += 32) {
    const int gi = (ks >> 3) + quad;
    bf16x8 a = *(const bf16x8*)&lds.A[(lr << 7) + ((gi ^ lr) << 3)];
#pragma unroll
    for (int j = 0; j < 2; ++j) {
      int col = (w << 5) + (j << 4) + lr;
      bf16x8 b = *(const bf16x8*)&WhImg[(col << 7) + (gi << 3)];
      c[j] = __builtin_amdgcn_mfma_f32_16x16x32_bf16(a, b, c[j], 0, 0, 0);
    }
  }
  __syncthreads();  // A consumed
#pragma unroll
  for (int j = 0; j < 2; ++j) {
    int col = (w << 5) + (j << 4) + lr;
    float bias = bmsg[col];
    int g4 = col >> 2;
#pragma unroll
    for (int r = 0; r < 4; ++r) {
      int rr = (quad << 2) + r;
      lds.C[(rr << 7) + (((g4 ^ (rr & 7)) << 2) + (col & 3))] = c[j][r] + bias;
    }
  }
  __syncthreads();
  {
    const f32x4* C4 = (const f32x4*)lds.C;
    f32x4 v0 = C4[(srow << 5) + (((sq << 1) | 0) ^ (srow & 7))];
    f32x4 v1 = C4[(srow << 5) + (((sq << 1) | 1) ^ (srow & 7))];
    *(u16x8*)&Hp[((size_t)(row0 + srow) << 7) + (sq << 3)] = pack8(v0, v1);
  }
}

// K3 (in-place): out = dropout(relu(LN((acc+boundary) @ W_lin + b_lin)))
__global__ __launch_bounds__(256) void k_out(float* accout,
                                             const float* __restrict__ bnd,
                                             const u16* __restrict__ WlImg,
                                             const float* __restrict__ blin,
                                             const float* __restrict__ gam,
                                             const float* __restrict__ bet) {
  __shared__ union { u16 A[16 * 128]; float C[16 * 128]; } lds;  // 8 KB
  const int t = threadIdx.x;
  const int row0 = blockIdx.x << 4;
  const int srow = t >> 4, sq = t & 15;
  const int n = row0 + srow;
  {
    const float* ap = accout + ((size_t)n << 7) + (sq << 3);
    const float* bp = bnd + ((size_t)n << 7) + (sq << 3);
    f32x4 a0 = *(const f32x4*)ap, a1 = *(const f32x4*)(ap + 4);
    f32x4 b0 = *(const f32x4*)bp, b1 = *(const f32x4*)(bp + 4);
    *(u16x8*)&lds.A[(srow << 7) + ((sq ^ srow) << 3)] = pack8(a0 + b0, a1 + b1);
  }
  __syncthreads();
  const int lane = t & 63, w = t >> 6;
  const int quad = lane >> 4, lr = lane & 15;
  f32x4 c[2];
#pragma unroll
  for (int j = 0; j < 2; ++j) { f32x4 z = {0.f, 0.f, 0.f, 0.f}; c[j] = z; }
#pragma unroll
  for (int ks = 0; ks < 128; ks += 32) {
    const int gi = (ks >> 3) + quad;
    bf16x8 a = *(const bf16x8*)&lds.A[(lr << 7) + ((gi ^ lr) << 3)];
#pragma unroll
    for (int j = 0; j < 2; ++j) {
      int col = (w << 5) + (j << 4) + lr;
      bf16x8 b = *(const bf16x8*)&WlImg[(col << 7) + (gi << 3)];
      c[j] = __builtin_amdgcn_mfma_f32_16x16x32_bf16(a, b, c[j], 0, 0, 0);
    }
  }
  __syncthreads();  // A consumed
#pragma unroll
  for (int j = 0; j < 2; ++j) {
    int col = (w << 5) + (j << 4) + lr;
    float bias = blin[col];
    int g4 = col >> 2;
#pragma unroll
    for (int r = 0; r < 4; ++r) {
      int rr = (quad << 2) + r;
      lds.C[(rr << 7) + (((g4 ^ (rr & 7)) << 2) + (col & 3))] = c[j][r] + bias;
    }
  }
  __syncthreads();
  // LN + relu + dropout: 16 threads/row, thread sq owns cols sq*8..+7
  const f32x4* C4 = (const f32x4*)lds.C;
  f32x4 x0 = C4[(srow << 5) + (((sq << 1) | 0) ^ (srow & 7))];
  f32x4 x1 = C4[(srow << 5) + (((sq << 1) | 1) ^ (srow & 7))];
  float s1 = 0.f, s2 = 0.f;
#pragma unroll
  for (int m = 0; m < 4; ++m) {
    s1 += x0[m] + x1[m];
    s2 += x0[m] * x0[m] + x1[m] * x1[m];
  }
  s1 += __shfl_xor(s1, 1, 64); s1 += __shfl_xor(s1, 2, 64);
  s1 += __shfl_xor(s1, 4, 64); s1 += __shfl_xor(s1, 8, 64);
  s2 += __shfl_xor(s2, 1, 64); s2 += __shfl_xor(s2, 2, 64);
  s2 += __shfl_xor(s2, 4, 64); s2 += __shfl_xor(s2, 8, 64);
  const float mean = s1 * 0.0078125f;
  const float var = s2 * 0.0078125f - mean * mean;
  const float inv = 1.0f / sqrtf(var + 1e-5f);
  const int d0 = sq << 3;
  f32x4 gm0 = *(const f32x4*)(gam + d0), gm1 = *(const f32x4*)(gam + d0 + 4);
  f32x4 bb0 = *(const f32x4*)(bet + d0), bb1 = *(const f32x4*)(bet + d0 + 4);
  f32x4 o0, o1;
#pragma unroll
  for (int m = 0; m < 4; ++m) {
    float y0 = fmaxf((x0[m] - mean) * inv * gm0[m] + bb0[m], 0.f);
    float y1 = fmaxf((x1[m] - mean) * inv * gm1[m] + bb1[m], 0.f);
    uint32_t j0 = ((uint32_t)n << 7) + (uint32_t)(d0 + m);
    uint32_t j1 = j0 + 4u;
    o0[m] = jax_keep(j0) ? (y0 * (1.0f / 0.9f)) : 0.0f;
    o1[m] = jax_keep(j1) ? (y1 * (1.0f / 0.9f)) : 0.0f;
  }
  *(f32x4*)(accout + ((size_t)n << 7) + d0) = o0;
  *(f32x4*)(accout + ((size_t)n << 7) + d0 + 4) = o1;
}

extern "C" void kernel_launch(void* const* d_in, const int* in_sizes, int n_in,
                              void* d_out, int out_size, void* d_ws, size_t ws_size,
                              hipStream_t stream) {
  (void)in_sizes; (void)n_in; (void)out_size; (void)ws_size;
  const float* hidden = (const float*)d_in[0];
  const int*   ei     = (const int*)d_in[1];
  const float* attr   = (const float*)d_in[2];
  const float* tim    = (const float*)d_in[3];
  const float* bnd    = (const float*)d_in[4];
  const float* Wmsg   = (const float*)d_in[5];
  const float* bmsg   = (const float*)d_in[6];
  const float* Wlin   = (const float*)d_in[7];
  const float* blin   = (const float*)d_in[8];
  const float* gam    = (const float*)d_in[9];
  const float* bet    = (const float*)d_in[10];

  float* acc = (float*)d_out;  // [N,128] f32 accumulator, finalized in-place

  char* ws = (char*)d_ws;
  u16*      Hp     = (u16*)(ws + 0);              // 12,800,000
  u16*      WhImg  = (u16*)(ws + 12800000);       //     32,768
  u16*      WcImg  = (u16*)(ws + 12832768);       //     16,384
  u16*      WlImg  = (u16*)(ws + 12849152);       //     32,768
  uint32_t* deg    = (uint32_t*)(ws + 12881920);  //    200,000
  uint32_t* cursor = (uint32_t*)(ws + 13081920);  //    200,000
  uint32_t* bsum   = (uint32_t*)(ws + 13281920);  //      1,024
  uint32_t* ex     = (uint32_t*)(ws + 13282944);  //    200,000
  u32x2*    psd    = (u32x2*)(ws + 13482944);     //  4,000,000 (NE*8)
  // total 17,482,944 bytes

  k_prep  <<<dim3(16), dim3(256), 0, stream>>>(Wmsg, Wlin, WhImg, WcImg, WlImg, deg);
  k_hp    <<<dim3(NT16), dim3(256), 0, stream>>>(hidden, WhImg, bmsg, ei, deg, Hp, acc);
  k_scan1 <<<dim3(NBLK_N), dim3(256), 0, stream>>>(deg, ex, bsum);
  k_scan23<<<dim3(NBLK_N), dim3(256), 0, stream>>>(bsum, ex, cursor);
  k_perm  <<<dim3((NE + 255) / 256), dim3(256), 0, stream>>>(ei, cursor, psd);
  k_edge3 <<<dim3(NEB), dim3(256), 0, stream>>>(psd, attr, tim, WcImg, Hp, acc);
  k_out   <<<dim3(NT16), dim3(256), 0, stream>>>(acc, bnd, WlImg, blin, gam, bet);
}